// Round 5
// baseline (14892.633 us; speedup 1.0000x reference)
//
#include <hip/hip_runtime.h>

#define NB 32
#define T 256
#define NS 64
#define NC 32
#define NSC 96

static __device__ __forceinline__ float dot4(float4 a, float4 b){
    return fmaf(a.x,b.x, fmaf(a.y,b.y, fmaf(a.z,b.z, a.w*b.w)));
}
static __device__ __forceinline__ bool nf30(float x){ return !(fabsf(x) <= 1e30f); }

// Static device-global workspace; rewritten every call -> deterministic.
__device__ __align__(16) float g_KtG[(size_t)NB*T*NS*NC];   // [b][t][s][u], Kt[s][u]=K[u][s]
__device__ __align__(16) float g_kkG[(size_t)NB*T*NC];      // [b][t][u]
__device__ float g_diagF[NB];                               // 0 = clean, else diag code

// ---------------------------------------------------------------------------
// Backward Riccati (policy evaluation form): one block (512 thr) per batch.
// ~61 KB LDS. Diag code: stage*1e13 + t*1e10 + b*1e8
//  2: Q[t]/p[t] load non-finite     3: assembled Qh non-finite
//  4: Quu inverse failed residual   5: anything >1e30
//  6: V-path onset (>1e8)           7: v-path onset (>1e8)
// ---------------------------------------------------------------------------
__global__ __launch_bounds__(512)
void lqr_bwd(const float* __restrict__ Qg_, const float* __restrict__ pg_,
             const float* __restrict__ Ag_, const float* __restrict__ Bg_,
             const float* __restrict__ c1g_, const float* __restrict__ x0g_,
             float* __restrict__ outc)
{
    __shared__ __align__(16) float Fo[64][96];   // F[s][j] (A|B)
    __shared__ __align__(16) float V[64][68];    // carry V; rows 0..31 overlay Maug; Gt staged here
    __shared__ __align__(16) float WK[64][36];   // W32 (passes) then Kt
    __shared__ __align__(16) float Qxu[64][36];
    __shared__ __align__(16) float prow[64];
    __shared__ __align__(16) float pfac[32];
    __shared__ __align__(16) float qh[96];
    __shared__ __align__(16) float gv[64];
    __shared__ __align__(16) float hbuf[32];     // h = qu + Quu*kk
    __shared__ __align__(16) float c1l[64];
    __shared__ __align__(16) float vl[64];
    __shared__ __align__(16) float kkl[32];
    __shared__ __align__(16) float x0l[64];
    __shared__ float wAcc;
    __shared__ int diagS;

    float (*Maug)[68] = reinterpret_cast<float (*)[68]>(&V[0][0]); // 32x68 overlay

    const int tid = threadIdx.x;
    const int b   = blockIdx.x;

    const float* Qg = Qg_ + (size_t)b*T*NSC*NSC;
    const float* pg = pg_ + (size_t)b*T*NSC;
    const float* Ag = Ag_ + (size_t)b*NS*NS;
    const float* Bg = Bg_ + (size_t)b*NS*NC;
    float* KtG = g_KtG + (size_t)b*T*NS*NC;
    float* kkG = g_kkG + (size_t)b*T*NC;

    // ---- init
    for (int e = tid; e < NS*NS; e += 512) { int s = e>>6, j = e&63; Fo[s][j] = Ag[e]; }
    for (int e = tid; e < NS*NC; e += 512) { int s = e>>5, u = e&31; Fo[s][64+u] = Bg[e]; }
    for (int e = tid; e < 64*68; e += 512) ((float*)V)[e] = 0.f;
    if (tid < 64) { c1l[tid] = c1g_[b*64+tid]; vl[tid] = 0.f; x0l[tid] = x0g_[b*64+tid]; }
    if (tid == 0) { wAcc = 0.f; diagS = 99; }
    __syncthreads();

    int tbreak = -1, scode = 0;
    for (int t = T-1; t >= 0; --t) {
        const float* Qt = Qg + (size_t)t*NSC*NSC;
        const float* pt = pg + (size_t)t*NSC;
        int bm = 0;
        float qxxA[4], qxxB[4];

        // ---- A0: gv = V*c1 + v ; wAcc += 0.5*c1'Vc1 + v'c1
        if (tid < 64) {
            float d = 0.f;
            #pragma unroll
            for (int k4 = 0; k4 < 16; ++k4)
                d += dot4(*(const float4*)&V[tid][k4*4], *(const float4*)&c1l[k4*4]);
            gv[tid] = d + vl[tid];
            float ps = c1l[tid]*(0.5f*d + vl[tid]);
            ps += __shfl_xor(ps,32); ps += __shfl_xor(ps,16); ps += __shfl_xor(ps,8);
            ps += __shfl_xor(ps,4);  ps += __shfl_xor(ps,2);  ps += __shfl_xor(ps,1);
            if (tid == 0) wAcc += ps;
        }
        __syncthreads();

        // ---- qh[j] = pt[j] + sum_s F[s][j]*gv[s]
        if (tid < 96) {
            const int j = tid;
            float q = pt[j];
            if (nf30(q)) bm |= 2;
            for (int s = 0; s < 64; ++s) q = fmaf(Fo[s][j], gv[s], q);
            if (nf30(q)) bm |= 4;
            qh[j] = q;
        }
        __syncthreads();

        // ======== pass jb=0: cols 0..31 of Qh -> qxxA ========
        {
            const int jj = tid & 31, s0 = (tid>>5)*4;
            float a0=0,a1=0,a2=0,a3=0;
            for (int k = 0; k < 64; ++k) {
                const float f = Fo[k][jj];
                const float4 v4 = *(const float4*)&V[k][s0];
                a0 = fmaf(v4.x,f,a0); a1 = fmaf(v4.y,f,a1);
                a2 = fmaf(v4.z,f,a2); a3 = fmaf(v4.w,f,a3);
            }
            WK[s0+0][jj]=a0; WK[s0+1][jj]=a1; WK[s0+2][jj]=a2; WK[s0+3][jj]=a3;
        }
        __syncthreads();
        {
            const int jj = tid & 31, i0 = (tid>>5)*4;
            float c0=0,c1_=0,c2=0,c3=0;
            for (int s = 0; s < 64; ++s) {
                const float w = WK[s][jj];
                const float4 a4 = *(const float4*)&Fo[s][i0];
                c0 = fmaf(a4.x,w,c0); c1_ = fmaf(a4.y,w,c1_);
                c2 = fmaf(a4.z,w,c2); c3 = fmaf(a4.w,w,c3);
            }
            const float q0 = Qt[(size_t)(i0+0)*96 + jj];
            const float q1 = Qt[(size_t)(i0+1)*96 + jj];
            const float q2 = Qt[(size_t)(i0+2)*96 + jj];
            const float q3 = Qt[(size_t)(i0+3)*96 + jj];
            if (nf30(q0)|nf30(q1)|nf30(q2)|nf30(q3)) bm |= 2;
            qxxA[0]=c0+q0; qxxA[1]=c1_+q1; qxxA[2]=c2+q2; qxxA[3]=c3+q3;
            if (nf30(qxxA[0])|nf30(qxxA[1])|nf30(qxxA[2])|nf30(qxxA[3])) bm |= 4;
        }
        __syncthreads();

        // ======== pass jb=1: cols 32..63 -> qxxB ========
        {
            const int jj = tid & 31, s0 = (tid>>5)*4;
            float a0=0,a1=0,a2=0,a3=0;
            for (int k = 0; k < 64; ++k) {
                const float f = Fo[k][32+jj];
                const float4 v4 = *(const float4*)&V[k][s0];
                a0 = fmaf(v4.x,f,a0); a1 = fmaf(v4.y,f,a1);
                a2 = fmaf(v4.z,f,a2); a3 = fmaf(v4.w,f,a3);
            }
            WK[s0+0][jj]=a0; WK[s0+1][jj]=a1; WK[s0+2][jj]=a2; WK[s0+3][jj]=a3;
        }
        __syncthreads();
        {
            const int jj = tid & 31, i0 = (tid>>5)*4;
            float c0=0,c1_=0,c2=0,c3=0;
            for (int s = 0; s < 64; ++s) {
                const float w = WK[s][jj];
                const float4 a4 = *(const float4*)&Fo[s][i0];
                c0 = fmaf(a4.x,w,c0); c1_ = fmaf(a4.y,w,c1_);
                c2 = fmaf(a4.z,w,c2); c3 = fmaf(a4.w,w,c3);
            }
            const float q0 = Qt[(size_t)(i0+0)*96 + 32 + jj];
            const float q1 = Qt[(size_t)(i0+1)*96 + 32 + jj];
            const float q2 = Qt[(size_t)(i0+2)*96 + 32 + jj];
            const float q3 = Qt[(size_t)(i0+3)*96 + 32 + jj];
            if (nf30(q0)|nf30(q1)|nf30(q2)|nf30(q3)) bm |= 2;
            qxxB[0]=c0+q0; qxxB[1]=c1_+q1; qxxB[2]=c2+q2; qxxB[3]=c3+q3;
            if (nf30(qxxB[0])|nf30(qxxB[1])|nf30(qxxB[2])|nf30(qxxB[3])) bm |= 4;
        }
        __syncthreads();

        // ======== pass jb=2: cols 64..95 -> Qxu, Quu->Maug, I->Maug[:,32:] ====
        {
            const int jj = tid & 31, s0 = (tid>>5)*4;
            float a0=0,a1=0,a2=0,a3=0;
            for (int k = 0; k < 64; ++k) {
                const float f = Fo[k][64+jj];
                const float4 v4 = *(const float4*)&V[k][s0];
                a0 = fmaf(v4.x,f,a0); a1 = fmaf(v4.y,f,a1);
                a2 = fmaf(v4.z,f,a2); a3 = fmaf(v4.w,f,a3);
            }
            WK[s0+0][jj]=a0; WK[s0+1][jj]=a1; WK[s0+2][jj]=a2; WK[s0+3][jj]=a3;
        }
        __syncthreads();
        {
            const int jj = tid & 31, i0 = (tid>>5)*4;
            float c0=0,c1_=0,c2=0,c3=0;
            for (int s = 0; s < 64; ++s) {
                const float w = WK[s][jj];
                const float4 a4 = *(const float4*)&Fo[s][i0];
                c0 = fmaf(a4.x,w,c0); c1_ = fmaf(a4.y,w,c1_);
                c2 = fmaf(a4.z,w,c2); c3 = fmaf(a4.w,w,c3);
            }
            const float q0 = Qt[(size_t)(i0+0)*96 + 64 + jj];
            const float q1 = Qt[(size_t)(i0+1)*96 + 64 + jj];
            const float q2 = Qt[(size_t)(i0+2)*96 + 64 + jj];
            const float q3 = Qt[(size_t)(i0+3)*96 + 64 + jj];
            if (nf30(q0)|nf30(q1)|nf30(q2)|nf30(q3)) bm |= 2;
            const float v0=c0+q0, v1=c1_+q1, v2=c2+q2, v3=c3+q3;
            if (nf30(v0)|nf30(v1)|nf30(v2)|nf30(v3)) bm |= 4;
            Qxu[i0+0][jj]=v0; Qxu[i0+1][jj]=v1; Qxu[i0+2][jj]=v2; Qxu[i0+3][jj]=v3;

            if (tid < 256) {
                const int w0 = (tid>>5)*4;
                float d0=0,d1=0,d2=0,d3=0;
                for (int s = 0; s < 64; ++s) {
                    const float w = WK[s][jj];
                    const float4 b4 = *(const float4*)&Fo[s][64+w0];
                    d0 = fmaf(b4.x,w,d0); d1 = fmaf(b4.y,w,d1);
                    d2 = fmaf(b4.z,w,d2); d3 = fmaf(b4.w,w,d3);
                }
                const float u0q = Qt[(size_t)(64+w0+0)*96 + 64 + jj];
                const float u1q = Qt[(size_t)(64+w0+1)*96 + 64 + jj];
                const float u2q = Qt[(size_t)(64+w0+2)*96 + 64 + jj];
                const float u3q = Qt[(size_t)(64+w0+3)*96 + 64 + jj];
                if (nf30(u0q)|nf30(u1q)|nf30(u2q)|nf30(u3q)) bm |= 2;
                const float m0=d0+u0q, m1=d1+u1q, m2=d2+u2q, m3=d3+u3q;
                if (nf30(m0)|nf30(m1)|nf30(m2)|nf30(m3)) bm |= 4;
                Maug[w0+0][jj]=m0; Maug[w0+1][jj]=m1; Maug[w0+2][jj]=m2; Maug[w0+3][jj]=m3;
            } else {
                const int e = tid-256, u = e>>3, jc0 = (e&7)*4;
                Maug[u][32+jc0+0] = (jc0+0==u)?1.f:0.f;
                Maug[u][32+jc0+1] = (jc0+1==u)?1.f:0.f;
                Maug[u][32+jc0+2] = (jc0+2==u)?1.f:0.f;
                Maug[u][32+jc0+3] = (jc0+3==u)?1.f:0.f;
            }
        }
        __syncthreads();

        // ---- CP: save Quu into 2 regs/thread (reads precede first GJ write-barrier)
        const int ucp = tid >> 4, ccp = (tid & 15) * 2;
        const float quuA = Maug[ucp][ccp];
        const float quuB = Maug[ucp][ccp+1];

        // ---- GJ inversion of Quu (SPD) on Maug
        for (int k = 0; k < 32; ++k) {
            if (tid < 64) prow[tid] = Maug[k][tid];
            else if (tid < 96) pfac[tid-64] = Maug[tid-64][k];
            __syncthreads();
            if (tid == 0 && fabsf(prow[k]) < 1e-8f) bm |= 8;
            {
                const int u = tid >> 4, j0 = (tid & 15) * 4;
                const float pinv = 1.0f / prow[k];
                float4 m = *(const float4*)&Maug[u][j0];
                const float4 pr = *(const float4*)&prow[j0];
                if (u == k) {
                    m.x = pr.x*pinv; m.y = pr.y*pinv; m.z = pr.z*pinv; m.w = pr.w*pinv;
                } else {
                    const float fac = pfac[u]*pinv;
                    m.x = fmaf(-fac,pr.x,m.x); m.y = fmaf(-fac,pr.y,m.y);
                    m.z = fmaf(-fac,pr.z,m.z); m.w = fmaf(-fac,pr.w,m.w);
                }
                *(float4*)&Maug[u][j0] = m;
            }
            __syncthreads();
        }

        // ---- restore Quu into Maug[:,0:32] (identity block is dead)
        Maug[ucp][ccp]   = quuA;
        Maug[ucp][ccp+1] = quuB;
        __syncthreads();

        // ---- residual check (Quu*Minv ~ I) + D: Kt = -Qxu*Minv^T, kk = -Minv*qu
        {
            const int ur = tid >> 4, jp = (tid & 15) * 2;
            #pragma unroll
            for (int jr = 0; jr < 2; ++jr) {
                const int j = jp + jr;
                float r = (ur == j) ? -1.f : 0.f, am = 0.f;
                for (int w = 0; w < 32; ++w) {
                    const float q = Maug[ur][w];
                    am = fmaxf(am, fabsf(q));
                    r = fmaf(q, Maug[w][32+j], r);
                }
                if (fabsf(r) > 1e-2f*(am + 1.f)) bm |= 8;
            }
            const int i = tid >> 3, u0 = (tid & 7) * 4;
            float a0=0,a1=0,a2=0,a3=0;
            #pragma unroll
            for (int w4 = 0; w4 < 8; ++w4) {
                const int wb = w4*4;
                const float4 q4 = *(const float4*)&Qxu[i][wb];
                const float4 m0 = *(const float4*)&Maug[u0+0][32+wb];
                const float4 m1 = *(const float4*)&Maug[u0+1][32+wb];
                const float4 m2 = *(const float4*)&Maug[u0+2][32+wb];
                const float4 m3 = *(const float4*)&Maug[u0+3][32+wb];
                a0 -= dot4(q4,m0); a1 -= dot4(q4,m1);
                a2 -= dot4(q4,m2); a3 -= dot4(q4,m3);
            }
            const float mx = fmaxf(fmaxf(fabsf(a0),fabsf(a1)), fmaxf(fabsf(a2),fabsf(a3)));
            if (mx > 1e30f) bm |= 16; else if (mx > 1e8f) bm |= 32;
            *(float4*)&WK[i][u0] = make_float4(a0,a1,a2,a3);
            *(float4*)&KtG[(size_t)t*2048 + i*32 + u0] = make_float4(a0,a1,a2,a3);
            if (tid < 32) {
                float ka = 0.f;
                #pragma unroll
                for (int w4 = 0; w4 < 8; ++w4)
                    ka -= dot4(*(const float4*)&Maug[tid][32+w4*4], *(const float4*)&qh[64+w4*4]);
                if (nf30(ka)) bm |= 16; else if (fabsf(ka) > 1e8f) bm |= 64;
                kkl[tid] = ka;
                kkG[t*32 + tid] = ka;
            }
        }
        __syncthreads();

        // ---- D2a: G = Quu*K (regs), h = qu + Quu*kk (reg)
        const int u2 = tid >> 4, j0d = (tid & 15) * 4;
        float gg[4];
        {
            #pragma unroll
            for (int r = 0; r < 4; ++r) {
                float g = 0.f;
                #pragma unroll
                for (int c4 = 0; c4 < 8; ++c4)
                    g += dot4(*(const float4*)&Maug[u2][c4*4], *(const float4*)&WK[j0d+r][c4*4]);
                gg[r] = g;
            }
        }
        float hreg = 0.f;
        if (tid < 32) {
            hreg = qh[64+tid];
            #pragma unroll
            for (int c4 = 0; c4 < 8; ++c4)
                hreg += dot4(*(const float4*)&Maug[tid][c4*4], *(const float4*)&kkl[c4*4]);
        }
        __syncthreads();
        // ---- D2b: stage Gt[j][u] = G[u][j] into V rows (cols 0..31); hbuf
        V[j0d+0][u2] = gg[0]; V[j0d+1][u2] = gg[1];
        V[j0d+2][u2] = gg[2]; V[j0d+3][u2] = gg[3];
        if (tid < 32) hbuf[tid] = hreg;
        __syncthreads();

        // ---- E-accum: Vn = Qxx + Qxu*K + K'Qux + K'QuuK  (policy evaluation)
        float aA[4], aB[4];
        {
            const int jj = tid & 31, i0 = (tid>>5)*4;
            #pragma unroll
            for (int r = 0; r < 4; ++r) { aA[r]=qxxA[r]; aB[r]=qxxB[r]; }
            #pragma unroll
            for (int u4 = 0; u4 < 8; ++u4) {
                const int ub = u4*4;
                const float4 kjA = *(const float4*)&WK[jj][ub];
                const float4 kjB = *(const float4*)&WK[32+jj][ub];
                const float4 xjA = *(const float4*)&Qxu[jj][ub];
                const float4 xjB = *(const float4*)&Qxu[32+jj][ub];
                const float4 gjA = *(const float4*)&V[jj][ub];
                const float4 gjB = *(const float4*)&V[32+jj][ub];
                #pragma unroll
                for (int r = 0; r < 4; ++r) {
                    const float4 xi = *(const float4*)&Qxu[i0+r][ub];
                    const float4 ki = *(const float4*)&WK[i0+r][ub];
                    aA[r] += dot4(xi,kjA) + dot4(ki,xjA) + dot4(ki,gjA);
                    aB[r] += dot4(xi,kjB) + dot4(ki,xjB) + dot4(ki,gjB);
                }
            }
        }
        // fold in: vn = qx + Qxu*kk + K'h ; w += 0.5*kk'(h+qu)
        if (tid < 64) {
            float vv = qh[tid];
            #pragma unroll
            for (int u4 = 0; u4 < 8; ++u4) {
                vv += dot4(*(const float4*)&Qxu[tid][u4*4], *(const float4*)&kkl[u4*4]);
                vv += dot4(*(const float4*)&WK[tid][u4*4],  *(const float4*)&hbuf[u4*4]);
            }
            if (nf30(vv)) bm |= 16; else if (fabsf(vv) > 1e8f) bm |= 64;
            vl[tid] = vv;
        } else if (tid < 96) {
            const int u = tid - 64;
            float r = kkl[u]*(hbuf[u] + qh[64+u]);
            r += __shfl_xor(r,16); r += __shfl_xor(r,8); r += __shfl_xor(r,4);
            r += __shfl_xor(r,2);  r += __shfl_xor(r,1);
            if (u == 0) wAcc += 0.5f*r;
        }
        __syncthreads();

        // ---- E-write: V <- Vn (+ growth checks)
        {
            const int jj = tid & 31, i0 = (tid>>5)*4;
            float mx = 0.f;
            #pragma unroll
            for (int r = 0; r < 4; ++r) {
                mx = fmaxf(mx, fmaxf(fabsf(aA[r]), fabsf(aB[r])));
                V[i0+r][jj]    = aA[r];
                V[i0+r][32+jj] = aB[r];
            }
            if (mx > 1e30f) bm |= 16; else if (mx > 1e8f) bm |= 32;
        }
        __syncthreads();

        // ---- symmetrize V
        for (int e = tid; e < 4096; e += 512) {
            const int i = e >> 6, j = e & 63;
            if (i < j) {
                const float av = 0.5f*(V[i][j] + V[j][i]);
                V[i][j] = av; V[j][i] = av;
            }
        }
        if (bm) {
            const int stg = (bm&2)?2 : (bm&4)?3 : (bm&8)?4 : (bm&16)?5 : (bm&32)?6 : 7;
            atomicMin(&diagS, stg);
        }
        __syncthreads();
        if (diagS < 99) { scode = diagS; tbreak = t; break; }
    }

    if (tbreak >= 0) {
        if (tid == 0) {
            g_diagF[b] = (float)scode*1e13f + (float)tbreak*1e10f + (float)b*1e8f;
            outc[b] = 0.f;
        }
        return;
    }

    // ---- cost[b] = wAcc + 0.5*x0'V0 x0 + v0'x0
    if (tid < 64) {
        float rd = 0.f;
        #pragma unroll
        for (int k4 = 0; k4 < 16; ++k4)
            rd += dot4(*(const float4*)&V[tid][k4*4], *(const float4*)&x0l[k4*4]);
        float ps = x0l[tid]*(0.5f*rd + vl[tid]);
        ps += __shfl_xor(ps,32); ps += __shfl_xor(ps,16); ps += __shfl_xor(ps,8);
        ps += __shfl_xor(ps,4);  ps += __shfl_xor(ps,2);  ps += __shfl_xor(ps,1);
        if (tid == 0) { outc[b] = wAcc + ps; g_diagF[b] = 0.f; }
    }
}

// ---------------------------------------------------------------------------
// Forward rollout: one block (64 threads) per batch.
// ---------------------------------------------------------------------------
__global__ __launch_bounds__(64)
void lqr_fwd(const float* __restrict__ Ag_, const float* __restrict__ Bg_,
             const float* __restrict__ c1g_, const float* __restrict__ x0g_,
             float* __restrict__ outx, float* __restrict__ outu)
{
    __shared__ __align__(16) float At[64][68];
    __shared__ __align__(16) float Bt[32][68];
    __shared__ __align__(16) float KtL[64][36];
    __shared__ float xl[64], ul[32], cl[64];
    __shared__ int fbad;

    const int lane = threadIdx.x;
    const int b = blockIdx.x;

    const float dg = g_diagF[b];
    if (dg != 0.f) {
        for (int t = 0; t < T; ++t) {
            outx[((size_t)b*T + t)*64 + lane] = (t==0 && lane==0) ? dg : 0.f;
            if (lane < 32) outu[((size_t)b*T + t)*32 + lane] = 0.f;
        }
        return;
    }

    const float* KtG = g_KtG + (size_t)b*T*NS*NC;
    const float* kkG = g_kkG + (size_t)b*T*NC;

    for (int e = lane; e < NS*NS; e += 64) { int i = e>>6, j = e&63; At[j][i] = Ag_[(size_t)b*4096 + e]; }
    for (int e = lane; e < NS*NC; e += 64) { int i = e>>5, w = e&31; Bt[w][i] = Bg_[(size_t)b*2048 + e]; }
    xl[lane] = x0g_[b*64 + lane];
    cl[lane] = c1g_[b*64 + lane];
    if (lane == 0) fbad = T;
    __syncthreads();

    for (int t = 0; t < T; ++t) {
        #pragma unroll
        for (int r = 0; r < 8; ++r) {
            const int idx = r*256 + lane*4;
            float4 g = *(const float4*)&KtG[(size_t)t*2048 + idx];
            const int s = idx >> 5, u0 = idx & 31;
            *(float4*)&KtL[s][u0] = g;
        }
        float ku = (lane < 32) ? kkG[t*32 + lane] : 0.f;
        __syncthreads();

        float xv = xl[lane];
        if (nf30(xv)) { xv = 0.f; atomicMin(&fbad, t); }
        outx[((size_t)b*T + t)*64 + lane] = xv;

        if (lane < 32) {
            float uu = ku;
            #pragma unroll
            for (int s = 0; s < 64; ++s) uu = fmaf(KtL[s][lane], xl[s], uu);
            ul[lane] = uu;
            float uo = uu;
            if (nf30(uo)) { uo = 0.f; atomicMin(&fbad, t); }
            outu[((size_t)b*T + t)*32 + lane] = uo;
        }
        __syncthreads();

        float xn = cl[lane];
        #pragma unroll
        for (int j = 0; j < 64; ++j) xn = fmaf(At[j][lane], xl[j], xn);
        #pragma unroll
        for (int w = 0; w < 32; ++w) xn = fmaf(Bt[w][lane], ul[w], xn);
        __syncthreads();
        xl[lane] = xn;
        __syncthreads();
    }

    __syncthreads();
    if (fbad < T && lane == 0)  // NaN born in rollout: small finite code (< any bwd code)
        outx[(size_t)b*T*64] = 9e12f + (float)fbad*1e9f + (float)b*1e6f;
}

// ---------------------------------------------------------------------------
extern "C" void kernel_launch(void* const* d_in, const int* in_sizes, int n_in,
                              void* d_out, int out_size, void* d_ws, size_t ws_size,
                              hipStream_t stream)
{
    const float* Q  = (const float*)d_in[0];
    const float* p  = (const float*)d_in[1];
    const float* A  = (const float*)d_in[2];
    const float* B  = (const float*)d_in[3];
    const float* c1 = (const float*)d_in[4];
    const float* x0 = (const float*)d_in[5];

    float* outx = (float*)d_out;                       // (NB,T,NS)
    float* outu = outx + (size_t)NB*T*NS;              // (NB,T,NC)
    float* outc = outu + (size_t)NB*T*NC;              // (NB,)

    lqr_bwd<<<NB, 512, 0, stream>>>(Q, p, A, B, c1, x0, outc);
    lqr_fwd<<<NB, 64, 0, stream>>>(A, B, c1, x0, outx, outu);
}

// Round 6
// 6565.582 us; speedup vs baseline: 2.2683x; 2.2683x over previous
//
#include <hip/hip_runtime.h>

#define NB 32
#define T 256
#define NS 64
#define NC 32
#define NSC 96

static __device__ __forceinline__ float dot4(float4 a, float4 b){
    return fmaf(a.x,b.x, fmaf(a.y,b.y, fmaf(a.z,b.z, a.w*b.w)));
}

// Static device-global workspace; fully rewritten every call -> deterministic.
__device__ __align__(16) float g_KtG[(size_t)NB*T*NS*NC];   // [b][t][s][u], Kt[s][u]=K[u][s]
__device__ __align__(16) float g_kkG[(size_t)NB*T*NC];      // [b][t][u]

// ---------------------------------------------------------------------------
// Backward Riccati (policy-evaluation form, identical math to the R5 pass):
// one block (512 threads) per batch, ~109 KB LDS, 1 block/CU.
// ---------------------------------------------------------------------------
__global__ __launch_bounds__(512, 2)
void lqr_bwd(const float* __restrict__ Qg_, const float* __restrict__ pg_,
             const float* __restrict__ Ag_, const float* __restrict__ Bg_,
             const float* __restrict__ c1g_, const float* __restrict__ x0g_,
             float* __restrict__ outc)
{
    __shared__ __align__(16) float Fo[64][100];  // F[s][j] (A|B), j<96
    __shared__ __align__(16) float V[64][68];    // carry V; holds Qxx between P2 and E
    __shared__ __align__(16) float W[64][100];   // W = V*F (full 96 cols)
    __shared__ __align__(16) float Qxu[64][36];
    __shared__ __align__(16) float QuuC[32][36]; // Quu copy (survives GJ)
    __shared__ __align__(16) float Maug[32][68]; // [Quu | I] -> [I | Quu^-1]
    __shared__ __align__(16) float Kt[64][36];   // Kt[s][u] = K[u][s]
    __shared__ __align__(16) float Gt[64][36];   // Gt[j][u] = (Quu*K)[u][j]
    __shared__ __align__(16) float prow[64];
    __shared__ __align__(16) float pfac[32];
    __shared__ __align__(16) float qh[96];
    __shared__ __align__(16) float gv[64];
    __shared__ __align__(16) float hbuf[32];     // h = qu + Quu*kk
    __shared__ __align__(16) float c1l[64];
    __shared__ __align__(16) float vl[64];
    __shared__ __align__(16) float kkl[32];
    __shared__ __align__(16) float x0l[64];
    __shared__ float wAcc;

    const int tid = threadIdx.x;
    const int b   = blockIdx.x;

    const float* Qg = Qg_ + (size_t)b*T*NSC*NSC;
    const float* pg = pg_ + (size_t)b*T*NSC;
    const float* Ag = Ag_ + (size_t)b*NS*NS;
    const float* Bg = Bg_ + (size_t)b*NS*NC;
    float* KtG = g_KtG + (size_t)b*T*NS*NC;
    float* kkG = g_kkG + (size_t)b*T*NC;

    // ---- init
    for (int e = tid; e < NS*NS; e += 512) { int s = e>>6, j = e&63; Fo[s][j] = Ag[e]; }
    for (int e = tid; e < NS*NC; e += 512) { int s = e>>5, u = e&31; Fo[s][64+u] = Bg[e]; }
    for (int e = tid; e < 64*68; e += 512) ((float*)V)[e] = 0.f;
    if (tid < 64) { c1l[tid] = c1g_[b*64+tid]; vl[tid] = 0.f; x0l[tid] = x0g_[b*64+tid]; }
    if (tid == 0) wAcc = 0.f;
    __syncthreads();

    const int jc = tid & 31;        // column group (GEMM phases)
    const int rg = tid >> 5;        // row group 0..15
    const int r0 = rg * 4;          // 4 rows per thread

    for (int t = T-1; t >= 0; --t) {
        const float* Qt = Qg + (size_t)t*NSC*NSC;
        const float* pt = pg + (size_t)t*NSC;

        // ---- P0: gv = V*c1 + v ; wAcc += 0.5*c1'Vc1 + v'c1   (carry V,v)
        if (tid < 64) {
            float d = 0.f;
            #pragma unroll
            for (int k4 = 0; k4 < 16; ++k4)
                d += dot4(*(const float4*)&V[tid][k4*4], *(const float4*)&c1l[k4*4]);
            gv[tid] = d + vl[tid];
            float ps = c1l[tid]*(0.5f*d + vl[tid]);
            ps += __shfl_xor(ps,32); ps += __shfl_xor(ps,16); ps += __shfl_xor(ps,8);
            ps += __shfl_xor(ps,4);  ps += __shfl_xor(ps,2);  ps += __shfl_xor(ps,1);
            if (tid == 0) wAcc += ps;
        }
        __syncthreads();

        // ---- P1: W[s][j] = sum_k V[k][s]*Fo[k][j] (V symmetric), all 96 cols
        //          + qh[j] = pt[j] + sum_s Fo[s][j]*gv[s]  (threads 0..95)
        {
            float aA[4] = {}, aB[4] = {}, aC[4] = {};
            #pragma unroll 8
            for (int k = 0; k < 64; ++k) {
                const float4 v4 = *(const float4*)&V[k][r0];
                const float fA = Fo[k][jc], fB = Fo[k][32+jc], fC = Fo[k][64+jc];
                aA[0]=fmaf(v4.x,fA,aA[0]); aA[1]=fmaf(v4.y,fA,aA[1]);
                aA[2]=fmaf(v4.z,fA,aA[2]); aA[3]=fmaf(v4.w,fA,aA[3]);
                aB[0]=fmaf(v4.x,fB,aB[0]); aB[1]=fmaf(v4.y,fB,aB[1]);
                aB[2]=fmaf(v4.z,fB,aB[2]); aB[3]=fmaf(v4.w,fB,aB[3]);
                aC[0]=fmaf(v4.x,fC,aC[0]); aC[1]=fmaf(v4.y,fC,aC[1]);
                aC[2]=fmaf(v4.z,fC,aC[2]); aC[3]=fmaf(v4.w,fC,aC[3]);
            }
            #pragma unroll
            for (int r = 0; r < 4; ++r) {
                W[r0+r][jc]    = aA[r];
                W[r0+r][32+jc] = aB[r];
                W[r0+r][64+jc] = aC[r];
            }
            if (tid < 96) {
                float q = pt[tid];
                #pragma unroll 8
                for (int s = 0; s < 64; ++s) q = fmaf(Fo[s][tid], gv[s], q);
                qh[tid] = q;
            }
        }
        __syncthreads();

        // ---- P2: Qh = Qt + F^T W.  Qxx -> V (in place), Qxu -> Qxu,
        //          Quu -> Maug[:,0:32] + QuuC, I -> Maug[:,32:64]
        {
            // prefetch Qt (global) so HBM latency hides under the k-loop
            float qtA[4], qtB[4], qtC[4];
            #pragma unroll
            for (int r = 0; r < 4; ++r) {
                qtA[r] = Qt[(size_t)(r0+r)*96 + jc];
                qtB[r] = Qt[(size_t)(r0+r)*96 + 32 + jc];
                qtC[r] = Qt[(size_t)(r0+r)*96 + 64 + jc];
            }
            const int wq = tid >> 4;          // 0..31 (Quu row)
            const int uq = (tid & 15) * 2;    // 0,2,..,30
            const float qq0 = Qt[(size_t)(64+wq)*96 + 64 + uq];
            const float qq1 = Qt[(size_t)(64+wq)*96 + 64 + uq + 1];

            float aA[4] = {}, aB[4] = {}, aC[4] = {};
            float q0 = 0.f, q1 = 0.f;
            #pragma unroll 8
            for (int s = 0; s < 64; ++s) {
                const float4 f4 = *(const float4*)&Fo[s][r0];
                const float wA = W[s][jc], wB = W[s][32+jc], wC = W[s][64+jc];
                aA[0]=fmaf(f4.x,wA,aA[0]); aA[1]=fmaf(f4.y,wA,aA[1]);
                aA[2]=fmaf(f4.z,wA,aA[2]); aA[3]=fmaf(f4.w,wA,aA[3]);
                aB[0]=fmaf(f4.x,wB,aB[0]); aB[1]=fmaf(f4.y,wB,aB[1]);
                aB[2]=fmaf(f4.z,wB,aB[2]); aB[3]=fmaf(f4.w,wB,aB[3]);
                aC[0]=fmaf(f4.x,wC,aC[0]); aC[1]=fmaf(f4.y,wC,aC[1]);
                aC[2]=fmaf(f4.z,wC,aC[2]); aC[3]=fmaf(f4.w,wC,aC[3]);
                const float fb = Fo[s][64+wq];
                q0 = fmaf(fb, W[s][64+uq],   q0);
                q1 = fmaf(fb, W[s][64+uq+1], q1);
            }
            #pragma unroll
            for (int r = 0; r < 4; ++r) {
                V[r0+r][jc]    = aA[r] + qtA[r];   // Qxx (in place; V is dead)
                V[r0+r][32+jc] = aB[r] + qtB[r];
                Qxu[r0+r][jc]  = aC[r] + qtC[r];
            }
            q0 += qq0; q1 += qq1;
            Maug[wq][uq]   = q0;  Maug[wq][uq+1]   = q1;
            QuuC[wq][uq]   = q0;  QuuC[wq][uq+1]   = q1;
            Maug[wq][32+uq]   = (uq   == wq) ? 1.f : 0.f;
            Maug[wq][32+uq+1] = (uq+1 == wq) ? 1.f : 0.f;
        }
        __syncthreads();

        // ---- P3: Gauss-Jordan inversion of Quu (SPD) on Maug
        for (int k = 0; k < 32; ++k) {
            if (tid < 64) prow[tid] = Maug[k][tid];
            else if (tid < 96) pfac[tid-64] = Maug[tid-64][k];
            __syncthreads();
            {
                const int u = tid >> 4, j0 = (tid & 15) * 4;
                const float pinv = 1.0f / prow[k];
                float4 m = *(const float4*)&Maug[u][j0];
                const float4 pr = *(const float4*)&prow[j0];
                if (u == k) {
                    m.x = pr.x*pinv; m.y = pr.y*pinv; m.z = pr.z*pinv; m.w = pr.w*pinv;
                } else {
                    const float fac = pfac[u]*pinv;
                    m.x = fmaf(-fac,pr.x,m.x); m.y = fmaf(-fac,pr.y,m.y);
                    m.z = fmaf(-fac,pr.z,m.z); m.w = fmaf(-fac,pr.w,m.w);
                }
                *(float4*)&Maug[u][j0] = m;
            }
            __syncthreads();
        }
        // Minv = Maug[:, 32:64]

        // ---- P4: Kt[i][u] = -sum_w Qxu[i][w]*Minv[u][w]; kk = -Minv*qu
        {
            const int i = tid >> 3, u0 = (tid & 7) * 4;
            float a0=0,a1=0,a2=0,a3=0;
            #pragma unroll
            for (int w4 = 0; w4 < 8; ++w4) {
                const int wb = w4*4;
                const float4 q4 = *(const float4*)&Qxu[i][wb];
                const float4 m0 = *(const float4*)&Maug[u0+0][32+wb];
                const float4 m1 = *(const float4*)&Maug[u0+1][32+wb];
                const float4 m2 = *(const float4*)&Maug[u0+2][32+wb];
                const float4 m3 = *(const float4*)&Maug[u0+3][32+wb];
                a0 -= dot4(q4,m0); a1 -= dot4(q4,m1);
                a2 -= dot4(q4,m2); a3 -= dot4(q4,m3);
            }
            const float4 kt4 = make_float4(a0,a1,a2,a3);
            *(float4*)&Kt[i][u0] = kt4;
            *(float4*)&KtG[(size_t)t*2048 + i*32 + u0] = kt4;
            if (tid < 32) {
                float ka = 0.f;
                #pragma unroll
                for (int w4 = 0; w4 < 8; ++w4)
                    ka -= dot4(*(const float4*)&Maug[tid][32+w4*4], *(const float4*)&qh[64+w4*4]);
                kkl[tid] = ka;
                kkG[t*32 + tid] = ka;
            }
        }
        __syncthreads();

        // ---- P5: Gt[j][u] = sum_w Quu[u][w]*Kt[j][w]; h = qu + Quu*kk
        {
            const int j = tid >> 3, u0 = (tid & 7) * 4;
            float g0=0,g1=0,g2=0,g3=0;
            #pragma unroll
            for (int w4 = 0; w4 < 8; ++w4) {
                const int wb = w4*4;
                const float4 k4 = *(const float4*)&Kt[j][wb];
                g0 += dot4(*(const float4*)&QuuC[u0+0][wb], k4);
                g1 += dot4(*(const float4*)&QuuC[u0+1][wb], k4);
                g2 += dot4(*(const float4*)&QuuC[u0+2][wb], k4);
                g3 += dot4(*(const float4*)&QuuC[u0+3][wb], k4);
            }
            *(float4*)&Gt[j][u0] = make_float4(g0,g1,g2,g3);
            if (tid < 32) {
                float h = qh[64+tid];
                #pragma unroll
                for (int w4 = 0; w4 < 8; ++w4)
                    h += dot4(*(const float4*)&QuuC[tid][w4*4], *(const float4*)&kkl[w4*4]);
                hbuf[tid] = h;
            }
        }
        __syncthreads();

        // ---- P6 (E): V <- Qxx + Qxu*K + K'Qux + K'QuuK  (policy evaluation)
        //      vn = qx + Qxu*kk + K'h ; wAcc += 0.5*kk'(h+qu)
        {
            const int jj = tid & 31, i0 = (tid >> 5) * 4;
            float aA[4], aB[4];
            #pragma unroll
            for (int r = 0; r < 4; ++r) { aA[r] = V[i0+r][jj]; aB[r] = V[i0+r][32+jj]; }
            #pragma unroll
            for (int u4 = 0; u4 < 8; ++u4) {
                const int ub = u4*4;
                const float4 kjA = *(const float4*)&Kt[jj][ub];
                const float4 kjB = *(const float4*)&Kt[32+jj][ub];
                const float4 xjA = *(const float4*)&Qxu[jj][ub];
                const float4 xjB = *(const float4*)&Qxu[32+jj][ub];
                const float4 gjA = *(const float4*)&Gt[jj][ub];
                const float4 gjB = *(const float4*)&Gt[32+jj][ub];
                #pragma unroll
                for (int r = 0; r < 4; ++r) {
                    const float4 xi = *(const float4*)&Qxu[i0+r][ub];
                    const float4 ki = *(const float4*)&Kt[i0+r][ub];
                    aA[r] += dot4(xi,kjA) + dot4(ki,xjA) + dot4(ki,gjA);
                    aB[r] += dot4(xi,kjB) + dot4(ki,xjB) + dot4(ki,gjB);
                }
            }
            #pragma unroll
            for (int r = 0; r < 4; ++r) { V[i0+r][jj] = aA[r]; V[i0+r][32+jj] = aB[r]; }
        }
        if (tid < 64) {
            float vv = qh[tid];
            #pragma unroll
            for (int u4 = 0; u4 < 8; ++u4) {
                vv += dot4(*(const float4*)&Qxu[tid][u4*4], *(const float4*)&kkl[u4*4]);
                vv += dot4(*(const float4*)&Kt[tid][u4*4],  *(const float4*)&hbuf[u4*4]);
            }
            vl[tid] = vv;
        } else if (tid < 96) {
            const int u = tid - 64;
            float r = kkl[u]*(hbuf[u] + qh[64+u]);
            r += __shfl_xor(r,16); r += __shfl_xor(r,8); r += __shfl_xor(r,4);
            r += __shfl_xor(r,2);  r += __shfl_xor(r,1);
            if (u == 0) wAcc += 0.5f*r;
        }
        __syncthreads();

        // ---- symmetrize V
        for (int e = tid; e < 4096; e += 512) {
            const int i = e >> 6, j = e & 63;
            if (i < j) {
                const float av = 0.5f*(V[i][j] + V[j][i]);
                V[i][j] = av; V[j][i] = av;
            }
        }
        __syncthreads();
    }

    // ---- cost[b] = wAcc + 0.5*x0'V0 x0 + v0'x0
    if (tid < 64) {
        float rd = 0.f;
        #pragma unroll
        for (int k4 = 0; k4 < 16; ++k4)
            rd += dot4(*(const float4*)&V[tid][k4*4], *(const float4*)&x0l[k4*4]);
        float ps = x0l[tid]*(0.5f*rd + vl[tid]);
        ps += __shfl_xor(ps,32); ps += __shfl_xor(ps,16); ps += __shfl_xor(ps,8);
        ps += __shfl_xor(ps,4);  ps += __shfl_xor(ps,2);  ps += __shfl_xor(ps,1);
        if (tid == 0) outc[b] = wAcc + ps;
    }
}

// ---------------------------------------------------------------------------
// Forward rollout: one block (64 threads) per batch.
// ---------------------------------------------------------------------------
__global__ __launch_bounds__(64)
void lqr_fwd(const float* __restrict__ Ag_, const float* __restrict__ Bg_,
             const float* __restrict__ c1g_, const float* __restrict__ x0g_,
             float* __restrict__ outx, float* __restrict__ outu)
{
    __shared__ __align__(16) float At[64][68];
    __shared__ __align__(16) float Bt[32][68];
    __shared__ __align__(16) float KtL[64][36];
    __shared__ float xl[64], ul[32], cl[64];

    const int lane = threadIdx.x;
    const int b = blockIdx.x;

    const float* KtG = g_KtG + (size_t)b*T*NS*NC;
    const float* kkG = g_kkG + (size_t)b*T*NC;

    for (int e = lane; e < NS*NS; e += 64) { int i = e>>6, j = e&63; At[j][i] = Ag_[(size_t)b*4096 + e]; }
    for (int e = lane; e < NS*NC; e += 64) { int i = e>>5, w = e&31; Bt[w][i] = Bg_[(size_t)b*2048 + e]; }
    xl[lane] = x0g_[b*64 + lane];
    cl[lane] = c1g_[b*64 + lane];
    __syncthreads();

    for (int t = 0; t < T; ++t) {
        #pragma unroll
        for (int r = 0; r < 8; ++r) {
            const int idx = r*256 + lane*4;
            const float4 g = *(const float4*)&KtG[(size_t)t*2048 + idx];
            *(float4*)&KtL[idx >> 5][idx & 31] = g;
        }
        const float ku = (lane < 32) ? kkG[t*32 + lane] : 0.f;
        __syncthreads();

        outx[((size_t)b*T + t)*64 + lane] = xl[lane];
        if (lane < 32) {
            float uu = ku;
            #pragma unroll 16
            for (int s = 0; s < 64; ++s) uu = fmaf(KtL[s][lane], xl[s], uu);
            ul[lane] = uu;
            outu[((size_t)b*T + t)*32 + lane] = uu;
        }
        __syncthreads();

        float xn = cl[lane];
        #pragma unroll 16
        for (int j = 0; j < 64; ++j) xn = fmaf(At[j][lane], xl[j], xn);
        #pragma unroll
        for (int w = 0; w < 32; ++w) xn = fmaf(Bt[w][lane], ul[w], xn);
        __syncthreads();
        xl[lane] = xn;
        __syncthreads();
    }
}

// ---------------------------------------------------------------------------
extern "C" void kernel_launch(void* const* d_in, const int* in_sizes, int n_in,
                              void* d_out, int out_size, void* d_ws, size_t ws_size,
                              hipStream_t stream)
{
    const float* Q  = (const float*)d_in[0];
    const float* p  = (const float*)d_in[1];
    const float* A  = (const float*)d_in[2];
    const float* B  = (const float*)d_in[3];
    const float* c1 = (const float*)d_in[4];
    const float* x0 = (const float*)d_in[5];

    float* outx = (float*)d_out;                       // (NB,T,NS)
    float* outu = outx + (size_t)NB*T*NS;              // (NB,T,NC)
    float* outc = outu + (size_t)NB*T*NC;              // (NB,)

    lqr_bwd<<<NB, 512, 0, stream>>>(Q, p, A, B, c1, x0, outc);
    lqr_fwd<<<NB, 64, 0, stream>>>(A, B, c1, x0, outx, outu);
}